// Round 2
// baseline (324.680 us; speedup 1.0000x reference)
//
#include <hip/hip_runtime.h>
#include <cstddef>

#define NB  4096
#define TT  200
#define DD  64
#define NH1 80
#define NH2 40

typedef _Float16 half8 __attribute__((ext_vector_type(8)));
typedef float    f32x4 __attribute__((ext_vector_type(4)));

// ---- workspace layout (bytes) ----
// wQh [4096][80] f32 : q@(W1a+W1c) + b1
// wF1 : layer-1 B fragments, lane-major: [(n*4+s)*64 + lane] -> half8  (20480 B)
// wF2 : layer-2 B fragments, lane-major: [(n*3+s)*64 + lane] -> half8  (9216 B)
static const size_t OFF_QH = 0;
static const size_t OFF_F1 = (size_t)NB * NH1 * 4;
static const size_t OFF_F2 = OFF_F1 + (size_t)5 * 4 * 64 * 8 * 2;

__global__ void prep_weights(const float* __restrict__ W1, const float* __restrict__ W2,
                             _Float16* __restrict__ wF1, _Float16* __restrict__ wF2)
{
    const int tid = blockIdx.x * blockDim.x + threadIdx.x;
    const int stride = blockDim.x * gridDim.x;
    // layer-1 fragments: value = B[kk][h], h = n*16+(l&15), kk = s*32+(l>>4)*8+j
    for (int i = tid; i < 5 * 4 * 64 * 8; i += stride) {
        const int j = i & 7, l = (i >> 3) & 63, s = (i >> 9) & 3, n = i >> 11;
        const int h  = n * 16 + (l & 15);
        const int kk = s * 32 + (l >> 4) * 8 + j;
        const float w = (kk < 64) ? (W1[(64 + kk) * NH1 + h] - W1[(128 + kk) * NH1 + h])
                                  :  W1[(128 + kk) * NH1 + h];
        wF1[i] = (_Float16)w;
    }
    // layer-2 fragments: value = W2[kk][n2], n2 = n*16+(l&15), kk = s*32+(l>>4)*8+j
    for (int i = tid; i < 3 * 3 * 64 * 8; i += stride) {
        const int j = i & 7, l = (i >> 3) & 63;
        const int s = (i >> 9) % 3, n = i / 1536;
        const int kk = s * 32 + (l >> 4) * 8 + j;
        const int n2 = n * 16 + (l & 15);
        const float w = (kk < NH1 && n2 < NH2) ? W2[kk * NH2 + n2] : 0.f;
        wF2[i] = (_Float16)w;
    }
}

__global__ void prep_qh(const float* __restrict__ q, const float* __restrict__ W1,
                        const float* __restrict__ b1, float* __restrict__ wQh)
{
    const int idx = blockIdx.x * blockDim.x + threadIdx.x;
    if (idx >= NB * NH1) return;
    const int b = idx / NH1;
    const int h = idx - b * NH1;
    const float* qb = q + (size_t)b * DD;
    float acc = b1[h];
#pragma unroll 8
    for (int d = 0; d < DD; ++d)
        acc += qb[d] * (W1[d * NH1 + h] + W1[(128 + d) * NH1 + h]);
    wQh[idx] = acc;
}

__global__ __launch_bounds__(256, 4)
void attn_main(const float* __restrict__ q, const float* __restrict__ k,
               const float* __restrict__ v, const int* __restrict__ mask,
               const float* __restrict__ Wf, const float* __restrict__ b2g,
               const float* __restrict__ bf,
               const float* __restrict__ wQh, const _Float16* __restrict__ wF1,
               const _Float16* __restrict__ wF2, float* __restrict__ out)
{
    __shared__ __align__(16) _Float16 sWF1[5 * 4 * 64 * 8];   // 20480 B
    __shared__ __align__(16) char sPool[4 * 16 * 192];        // per-wave h1 (12288 B); reused as sVred
    __shared__ float sQh[80];
    __shared__ float sWf[48];
    __shared__ float sB2[48];
    __shared__ float sLogit[208];
    __shared__ float sAttn[208];
    __shared__ float sRed[8];

    const int b    = blockIdx.x;
    const int tid  = threadIdx.x;
    const int wid  = tid >> 6;
    const int lane = tid & 63;
    const int lr   = lane & 15;
    const int lg   = lane >> 4;
    const float bfv = bf[0];

    // hoisted mask load (coalesced, overlaps everything below)
    int mymask = 0;
    if (tid < TT) mymask = mask[(size_t)b * TT + tid];

    if (tid < 80)                  sQh[tid] = wQh[(size_t)b * NH1 + tid];
    else if (tid < 128) { const int c = tid - 80;  sWf[c] = (c < NH2) ? Wf[c]  : 0.f; }
    else if (tid < 176) { const int c = tid - 128; sB2[c] = (c < NH2) ? b2g[c] : 0.f; }

    // stage layer-1 weight fragments into LDS (lane-contiguous, conflict-free reads)
    {
        f32x4* dst = (f32x4*)sWF1;
        const f32x4* src = (const f32x4*)wF1;
        for (int i = tid; i < 1280; i += 256) dst[i] = src[i];
    }

    float qreg[16];
    {
        const float* qb = q + (size_t)b * DD;
#pragma unroll
        for (int j = 0; j < 8; ++j) qreg[j]     = qb[lg * 8 + j];
#pragma unroll
        for (int j = 0; j < 8; ++j) qreg[8 + j] = qb[32 + lg * 8 + j];
    }

    // zero-pad my wave's h1 cols 80..95 (slots 10,11), swizzled
    char* myH1 = sPool + wid * 3072;
    if (lane < 32) {
        const int row = lane >> 1;
        const int slotL = 10 + (lane & 1);
        const f32x4 z4 = {};
        *(f32x4*)(myH1 + row * 192 + ((slotL ^ (row & 3)) << 4)) = z4;
    }

    __syncthreads();   // sWF1 / sQh / sWf / sB2 ready

    const half8* sF1v = (const half8*)sWF1;
    const half8* gF2  = (const half8*)wF2;

    // ---- fused per-tile: layer1 -> per-wave LDS -> layer2 -> logits ----
    for (int mt = wid; mt < 13; mt += 4) {
        const int t = min(mt * 16 + lr, TT - 1);   // clamped; rows >=200 give discarded logits
        const float* krow = k + ((size_t)b * TT + t) * DD;
        const f32x4 kv0 = *(const f32x4*)(krow + lg * 8);
        const f32x4 kv1 = *(const f32x4*)(krow + lg * 8 + 4);
        const f32x4 kv2 = *(const f32x4*)(krow + 32 + lg * 8);
        const f32x4 kv3 = *(const f32x4*)(krow + 32 + lg * 8 + 4);

        half8 af[4];
#pragma unroll
        for (int j = 0; j < 4; ++j) {
            af[0][j] = (_Float16)kv0[j];                 af[0][j + 4] = (_Float16)kv1[j];
            af[1][j] = (_Float16)kv2[j];                 af[1][j + 4] = (_Float16)kv3[j];
            af[2][j] = (_Float16)(qreg[j]     * kv0[j]); af[2][j + 4] = (_Float16)(qreg[j + 4]  * kv1[j]);
            af[3][j] = (_Float16)(qreg[8 + j] * kv2[j]); af[3][j + 4] = (_Float16)(qreg[12 + j] * kv3[j]);
        }

        f32x4 acc[5] = {};
#pragma unroll
        for (int n = 0; n < 5; ++n)
#pragma unroll
            for (int s = 0; s < 4; ++s)
                acc[n] = __builtin_amdgcn_mfma_f32_16x16x32_f16(af[s], sF1v[(n * 4 + s) * 64 + lane], acc[n], 0, 0, 0);

        // epilogue: relu(acc + qh) -> per-wave swizzled f16 buffer
#pragma unroll
        for (int n = 0; n < 5; ++n) {
            const int hcol = n * 16 + lr;
            const float qh = sQh[hcol];
            const int slot   = hcol >> 3;
            const int within = (hcol & 7) * 2;
#pragma unroll
            for (int j = 0; j < 4; ++j) {
                const int r = lg * 4 + j;
                const float hv = fmaxf(acc[n][j] + qh, 0.f);
                *(_Float16*)(myH1 + r * 192 + ((slot ^ (r & 3)) << 4) + within) = (_Float16)hv;
            }
        }

        // layer 2 on this tile (reads only rows this wave just wrote)
        half8 a2[3];
#pragma unroll
        for (int s = 0; s < 3; ++s)
            a2[s] = *(const half8*)(myH1 + lr * 192 + (((s * 4 + lg) ^ (lr & 3)) << 4));

        f32x4 acc2[3] = {};
#pragma unroll
        for (int n = 0; n < 3; ++n)
#pragma unroll
            for (int s = 0; s < 3; ++s)
                acc2[n] = __builtin_amdgcn_mfma_f32_16x16x32_f16(a2[s], gF2[(n * 3 + s) * 64 + lane], acc2[n], 0, 0, 0);

        float p0 = 0.f, p1 = 0.f, p2 = 0.f, p3 = 0.f;
#pragma unroll
        for (int n = 0; n < 3; ++n) {
            const int hcol = n * 16 + lr;
            const float wf = sWf[hcol];
            const float bb = sB2[hcol];
            p0 += fmaxf(acc2[n][0] + bb, 0.f) * wf;
            p1 += fmaxf(acc2[n][1] + bb, 0.f) * wf;
            p2 += fmaxf(acc2[n][2] + bb, 0.f) * wf;
            p3 += fmaxf(acc2[n][3] + bb, 0.f) * wf;
        }
#pragma unroll
        for (int off = 1; off < 16; off <<= 1) {
            p0 += __shfl_xor(p0, off);
            p1 += __shfl_xor(p1, off);
            p2 += __shfl_xor(p2, off);
            p3 += __shfl_xor(p3, off);
        }
        if (lr == 0) {
            const int rbase = mt * 16 + lg * 4;
            sLogit[rbase + 0] = p0 + bfv;
            sLogit[rbase + 1] = p1 + bfv;
            sLogit[rbase + 2] = p2 + bfv;
            sLogit[rbase + 3] = p3 + bfv;
        }
    }
    __syncthreads();

    // ---------------- masked softmax over T ----------------
    {
        const int t = tid;
        float lgv = -3.0e38f;
        if (t < TT) lgv = mymask ? sLogit[t] : -4294967295.0f;
        float m = lgv;
#pragma unroll
        for (int off = 32; off > 0; off >>= 1) m = fmaxf(m, __shfl_xor(m, off));
        if (lane == 0) sRed[wid] = m;
        __syncthreads();
        const float M = fmaxf(fmaxf(sRed[0], sRed[1]), fmaxf(sRed[2], sRed[3]));
        float e = (t < TT) ? __expf(lgv - M) : 0.f;
        float s = e;
#pragma unroll
        for (int off = 32; off > 0; off >>= 1) s += __shfl_xor(s, off);
        if (lane == 0) sRed[4 + wid] = s;
        __syncthreads();
        const float S = sRed[4] + sRed[5] + sRed[6] + sRed[7];
        if (t < TT) sAttn[t] = e / S;
    }
    __syncthreads();

    // ---------------- weighted sum over v ----------------
    float* sVred = (float*)sPool;   // h1 pool is dead now
    {
        const int dq = (tid & 15) * 4;
        const int g  = tid >> 4;
        const float* vb = v + (size_t)b * (TT * DD);
        f32x4 acc = {};
#pragma unroll
        for (int i = 0; i < 13; ++i) {
            const int t0 = g + i * 16;
            if (t0 < TT) {
                const f32x4 vv = *(const f32x4*)(vb + t0 * DD + dq);
                acc += vv * sAttn[t0];
            }
        }
        *(f32x4*)(&sVred[g * 64 + dq]) = acc;
    }
    __syncthreads();
    if (tid < 64) {
        float r = 0.f;
#pragma unroll
        for (int gg = 0; gg < 16; ++gg) r += sVred[gg * 64 + tid];
        out[(size_t)b * DD + tid] = r;
    }
}

extern "C" void kernel_launch(void* const* d_in, const int* in_sizes, int n_in,
                              void* d_out, int out_size, void* d_ws, size_t ws_size,
                              hipStream_t stream)
{
    const float* q   = (const float*)d_in[0];
    const float* k   = (const float*)d_in[1];
    const float* v   = (const float*)d_in[2];
    const int*  mask = (const int*)  d_in[3];
    const float* W1  = (const float*)d_in[4];
    const float* b1  = (const float*)d_in[5];
    const float* W2  = (const float*)d_in[6];
    const float* Wf  = (const float*)d_in[8];
    const float* bf  = (const float*)d_in[9];
    const float* b2  = (const float*)d_in[7];
    float* out = (float*)d_out;

    char* ws = (char*)d_ws;
    float*    wQh = (float*)   (ws + OFF_QH);
    _Float16* wF1 = (_Float16*)(ws + OFF_F1);
    _Float16* wF2 = (_Float16*)(ws + OFF_F2);

    prep_weights<<<16, 256, 0, stream>>>(W1, W2, wF1, wF2);
    prep_qh<<<(NB * NH1 + 255) / 256, 256, 0, stream>>>(q, W1, b1, wQh);
    attn_main<<<NB, 256, 0, stream>>>(q, k, v, mask, Wf, b2, bf, wQh, wF1, wF2, out);
}

// Round 3
// 274.982 us; speedup vs baseline: 1.1807x; 1.1807x over previous
//
#include <hip/hip_runtime.h>
#include <cstddef>

#define NB  4096
#define TT  200
#define DD  64
#define NH1 80
#define NH2 40

typedef _Float16 half8 __attribute__((ext_vector_type(8)));
typedef float    f32x4 __attribute__((ext_vector_type(4)));

// ---- workspace layout (bytes) ----
// wQh [4096][80] f32 : q@(W1a+W1c) + b1
// wF1 : layer-1 B fragments, lane-major: [(n*4+s)*64 + lane] -> half8  (20480 B)
// wF2 : layer-2 B fragments, lane-major: [(n*3+s)*64 + lane] -> half8  (9216 B)
static const size_t OFF_QH = 0;
static const size_t OFF_F1 = (size_t)NB * NH1 * 4;
static const size_t OFF_F2 = OFF_F1 + (size_t)5 * 4 * 64 * 8 * 2;

__global__ void prep_weights(const float* __restrict__ W1, const float* __restrict__ W2,
                             _Float16* __restrict__ wF1, _Float16* __restrict__ wF2)
{
    const int tid = blockIdx.x * blockDim.x + threadIdx.x;
    const int stride = blockDim.x * gridDim.x;
    // layer-1 fragments: value = B[kk][h], h = n*16+(l&15), kk = s*32+(l>>4)*8+j
    for (int i = tid; i < 5 * 4 * 64 * 8; i += stride) {
        const int j = i & 7, l = (i >> 3) & 63, s = (i >> 9) & 3, n = i >> 11;
        const int h  = n * 16 + (l & 15);
        const int kk = s * 32 + (l >> 4) * 8 + j;
        const float w = (kk < 64) ? (W1[(64 + kk) * NH1 + h] - W1[(128 + kk) * NH1 + h])
                                  :  W1[(128 + kk) * NH1 + h];
        wF1[i] = (_Float16)w;
    }
    // layer-2 fragments: value = W2[kk][n2], n2 = n*16+(l&15), kk = s*32+(l>>4)*8+j
    for (int i = tid; i < 3 * 3 * 64 * 8; i += stride) {
        const int j = i & 7, l = (i >> 3) & 63;
        const int s = (i >> 9) % 3, n = i / 1536;
        const int kk = s * 32 + (l >> 4) * 8 + j;
        const int n2 = n * 16 + (l & 15);
        const float w = (kk < NH1 && n2 < NH2) ? W2[kk * NH2 + n2] : 0.f;
        wF2[i] = (_Float16)w;
    }
}

__global__ void prep_qh(const float* __restrict__ q, const float* __restrict__ W1,
                        const float* __restrict__ b1, float* __restrict__ wQh)
{
    const int idx = blockIdx.x * blockDim.x + threadIdx.x;
    if (idx >= NB * NH1) return;
    const int b = idx / NH1;
    const int h = idx - b * NH1;
    const float* qb = q + (size_t)b * DD;
    float acc = b1[h];
#pragma unroll 8
    for (int d = 0; d < DD; ++d)
        acc += qb[d] * (W1[d * NH1 + h] + W1[(128 + d) * NH1 + h]);
    wQh[idx] = acc;
}

__global__ __launch_bounds__(256, 3)
void attn_main(const float* __restrict__ q, const float* __restrict__ k,
               const float* __restrict__ v, const int* __restrict__ mask,
               const float* __restrict__ Wf, const float* __restrict__ b2g,
               const float* __restrict__ bf,
               const float* __restrict__ wQh, const _Float16* __restrict__ wF1,
               const _Float16* __restrict__ wF2, float* __restrict__ out)
{
    __shared__ __align__(16) _Float16 sWF1[5 * 4 * 64 * 8];   // 20480 B
    __shared__ __align__(16) char sPool[4 * 16 * 192];        // per-wave h1 (12288 B); reused as sVred
    __shared__ float sQh[80];
    __shared__ float sWf[48];
    __shared__ float sB2[48];
    __shared__ float sLogit[208];
    __shared__ float sAttn[208];
    __shared__ float sRed[8];

    const int b    = blockIdx.x;
    const int tid  = threadIdx.x;
    const int wid  = tid >> 6;
    const int lane = tid & 63;
    const int lr   = lane & 15;
    const int lg   = lane >> 4;
    const float bfv = bf[0];

    // hoisted mask load (coalesced, overlaps everything below)
    int mymask = 0;
    if (tid < TT) mymask = mask[(size_t)b * TT + tid];

    if (tid < 80)                  sQh[tid] = wQh[(size_t)b * NH1 + tid];
    else if (tid < 128) { const int c = tid - 80;  sWf[c] = (c < NH2) ? Wf[c]  : 0.f; }
    else if (tid < 176) { const int c = tid - 128; sB2[c] = (c < NH2) ? b2g[c] : 0.f; }

    // stage layer-1 weight fragments into LDS (lane-contiguous, conflict-free reads)
    {
        f32x4* dst = (f32x4*)sWF1;
        const f32x4* src = (const f32x4*)wF1;
        for (int i = tid; i < 1280; i += 256) dst[i] = src[i];
    }

    // q held as packed fp16 (8 VGPRs): qh0 = q[lg*8..+7], qh1 = q[32+lg*8..+7]
    half8 qh0, qh1;
    {
        const float* qb = q + (size_t)b * DD;
#pragma unroll
        for (int j = 0; j < 8; ++j) qh0[j] = (_Float16)qb[lg * 8 + j];
#pragma unroll
        for (int j = 0; j < 8; ++j) qh1[j] = (_Float16)qb[32 + lg * 8 + j];
    }

    // zero-pad my wave's h1 cols 80..95 (slots 10,11), swizzled
    char* myH1 = sPool + wid * 3072;
    if (lane < 32) {
        const int row = lane >> 1;
        const int slotL = 10 + (lane & 1);
        const f32x4 z4 = {};
        *(f32x4*)(myH1 + row * 192 + ((slotL ^ (row & 3)) << 4)) = z4;
    }

    __syncthreads();   // sWF1 / sQh / sWf / sB2 ready

    const half8* sF1v = (const half8*)sWF1;
    const half8* gF2  = (const half8*)wF2;

    // ---- fused per-tile: layer1 -> per-wave LDS -> layer2 -> logits ----
    for (int mt = wid; mt < 13; mt += 4) {
        const int t = min(mt * 16 + lr, TT - 1);   // clamped; rows >=200 give discarded logits
        const float* krow = k + ((size_t)b * TT + t) * DD;
        const f32x4 kv0 = *(const f32x4*)(krow + lg * 8);
        const f32x4 kv1 = *(const f32x4*)(krow + lg * 8 + 4);
        const f32x4 kv2 = *(const f32x4*)(krow + 32 + lg * 8);
        const f32x4 kv3 = *(const f32x4*)(krow + 32 + lg * 8 + 4);

        half8 af[4];
#pragma unroll
        for (int j = 0; j < 4; ++j) {
            af[0][j] = (_Float16)kv0[j];  af[0][j + 4] = (_Float16)kv1[j];
            af[1][j] = (_Float16)kv2[j];  af[1][j + 4] = (_Float16)kv3[j];
        }
        af[2] = qh0 * af[0];   // packed fp16 multiplies (q*k)
        af[3] = qh1 * af[1];

        f32x4 acc[5] = {};
#pragma unroll
        for (int n = 0; n < 5; ++n)
#pragma unroll
            for (int s = 0; s < 4; ++s)
                acc[n] = __builtin_amdgcn_mfma_f32_16x16x32_f16(af[s], sF1v[(n * 4 + s) * 64 + lane], acc[n], 0, 0, 0);

        // epilogue: relu(acc + qh) -> per-wave swizzled f16 buffer
#pragma unroll
        for (int n = 0; n < 5; ++n) {
            const int hcol = n * 16 + lr;
            const float qh = sQh[hcol];
            const int slot   = hcol >> 3;
            const int within = (hcol & 7) * 2;
#pragma unroll
            for (int j = 0; j < 4; ++j) {
                const int r = lg * 4 + j;
                const float hv = fmaxf(acc[n][j] + qh, 0.f);
                *(_Float16*)(myH1 + r * 192 + ((slot ^ (r & 3)) << 4) + within) = (_Float16)hv;
            }
        }

        // layer 2 on this tile (reads only rows this wave just wrote)
        half8 a2[3];
#pragma unroll
        for (int s = 0; s < 3; ++s)
            a2[s] = *(const half8*)(myH1 + lr * 192 + (((s * 4 + lg) ^ (lr & 3)) << 4));

        f32x4 acc2[3] = {};
#pragma unroll
        for (int n = 0; n < 3; ++n)
#pragma unroll
            for (int s = 0; s < 3; ++s)
                acc2[n] = __builtin_amdgcn_mfma_f32_16x16x32_f16(a2[s], gF2[(n * 3 + s) * 64 + lane], acc2[n], 0, 0, 0);

        float p0 = 0.f, p1 = 0.f, p2 = 0.f, p3 = 0.f;
#pragma unroll
        for (int n = 0; n < 3; ++n) {
            const int hcol = n * 16 + lr;
            const float wf = sWf[hcol];
            const float bb = sB2[hcol];
            p0 += fmaxf(acc2[n][0] + bb, 0.f) * wf;
            p1 += fmaxf(acc2[n][1] + bb, 0.f) * wf;
            p2 += fmaxf(acc2[n][2] + bb, 0.f) * wf;
            p3 += fmaxf(acc2[n][3] + bb, 0.f) * wf;
        }
#pragma unroll
        for (int off = 1; off < 16; off <<= 1) {
            p0 += __shfl_xor(p0, off);
            p1 += __shfl_xor(p1, off);
            p2 += __shfl_xor(p2, off);
            p3 += __shfl_xor(p3, off);
        }
        if (lr == 0) {
            const int rbase = mt * 16 + lg * 4;
            sLogit[rbase + 0] = p0 + bfv;
            sLogit[rbase + 1] = p1 + bfv;
            sLogit[rbase + 2] = p2 + bfv;
            sLogit[rbase + 3] = p3 + bfv;
        }
    }
    __syncthreads();

    // ---------------- masked softmax over T ----------------
    {
        const int t = tid;
        float lgv = -3.0e38f;
        if (t < TT) lgv = mymask ? sLogit[t] : -4294967295.0f;
        float m = lgv;
#pragma unroll
        for (int off = 32; off > 0; off >>= 1) m = fmaxf(m, __shfl_xor(m, off));
        if (lane == 0) sRed[wid] = m;
        __syncthreads();
        const float M = fmaxf(fmaxf(sRed[0], sRed[1]), fmaxf(sRed[2], sRed[3]));
        float e = (t < TT) ? __expf(lgv - M) : 0.f;
        float s = e;
#pragma unroll
        for (int off = 32; off > 0; off >>= 1) s += __shfl_xor(s, off);
        if (lane == 0) sRed[4 + wid] = s;
        __syncthreads();
        const float S = sRed[4] + sRed[5] + sRed[6] + sRed[7];
        if (t < TT) sAttn[t] = e / S;
    }
    __syncthreads();

    // ---------------- weighted sum over v ----------------
    float* sVred = (float*)sPool;   // h1 pool is dead now
    {
        const int dq = (tid & 15) * 4;
        const int g  = tid >> 4;
        const float* vb = v + (size_t)b * (TT * DD);
        f32x4 acc = {};
#pragma unroll
        for (int i = 0; i < 13; ++i) {
            const int t0 = g + i * 16;
            if (t0 < TT) {
                const f32x4 vv = *(const f32x4*)(vb + t0 * DD + dq);
                acc += vv * sAttn[t0];
            }
        }
        *(f32x4*)(&sVred[g * 64 + dq]) = acc;
    }
    __syncthreads();
    if (tid < 64) {
        float r = 0.f;
#pragma unroll
        for (int gg = 0; gg < 16; ++gg) r += sVred[gg * 64 + tid];
        out[(size_t)b * DD + tid] = r;
    }
}

extern "C" void kernel_launch(void* const* d_in, const int* in_sizes, int n_in,
                              void* d_out, int out_size, void* d_ws, size_t ws_size,
                              hipStream_t stream)
{
    const float* q   = (const float*)d_in[0];
    const float* k   = (const float*)d_in[1];
    const float* v   = (const float*)d_in[2];
    const int*  mask = (const int*)  d_in[3];
    const float* W1  = (const float*)d_in[4];
    const float* b1  = (const float*)d_in[5];
    const float* W2  = (const float*)d_in[6];
    const float* b2  = (const float*)d_in[7];
    const float* Wf  = (const float*)d_in[8];
    const float* bf  = (const float*)d_in[9];
    float* out = (float*)d_out;

    char* ws = (char*)d_ws;
    float*    wQh = (float*)   (ws + OFF_QH);
    _Float16* wF1 = (_Float16*)(ws + OFF_F1);
    _Float16* wF2 = (_Float16*)(ws + OFF_F2);

    prep_weights<<<16, 256, 0, stream>>>(W1, W2, wF1, wF2);
    prep_qh<<<(NB * NH1 + 255) / 256, 256, 0, stream>>>(q, W1, b1, wQh);
    attn_main<<<NB, 256, 0, stream>>>(q, k, v, mask, Wf, b2, bf, wQh, wF1, wF2, out);
}

// Round 4
// 137.201 us; speedup vs baseline: 2.3665x; 2.0042x over previous
//
#include <hip/hip_runtime.h>
#include <cstddef>

#define NB  4096
#define TT  200
#define DD  64
#define NH1 80
#define NH2 40

typedef _Float16 half8 __attribute__((ext_vector_type(8)));
typedef float    f32x4 __attribute__((ext_vector_type(4)));

// ---- workspace layout (bytes) ----
// wQh [4096][80] f32 : q@(W1a+W1c) + b1
// wF1 : layer-1 B fragments, lane-major: [(n*4+s)*64 + lane] -> half8  (20480 B)
// wF2 : layer-2 B fragments, lane-major: [(n*3+s)*64 + lane] -> half8  (9216 B)
static const size_t OFF_QH = 0;
static const size_t OFF_F1 = (size_t)NB * NH1 * 4;
static const size_t OFF_F2 = OFF_F1 + (size_t)5 * 4 * 64 * 8 * 2;

__global__ void prep_weights(const float* __restrict__ W1, const float* __restrict__ W2,
                             _Float16* __restrict__ wF1, _Float16* __restrict__ wF2)
{
    const int tid = blockIdx.x * blockDim.x + threadIdx.x;
    const int stride = blockDim.x * gridDim.x;
    // layer-1 fragments: value = B[kk][h], h = n*16+(l&15), kk = s*32+(l>>4)*8+j
    for (int i = tid; i < 5 * 4 * 64 * 8; i += stride) {
        const int j = i & 7, l = (i >> 3) & 63, s = (i >> 9) & 3, n = i >> 11;
        const int h  = n * 16 + (l & 15);
        const int kk = s * 32 + (l >> 4) * 8 + j;
        const float w = (kk < 64) ? (W1[(64 + kk) * NH1 + h] - W1[(128 + kk) * NH1 + h])
                                  :  W1[(128 + kk) * NH1 + h];
        wF1[i] = (_Float16)w;
    }
    // layer-2 fragments: value = W2[kk][n2], n2 = n*16+(l&15), kk = s*32+(l>>4)*8+j
    for (int i = tid; i < 3 * 3 * 64 * 8; i += stride) {
        const int j = i & 7, l = (i >> 3) & 63;
        const int s = (i >> 9) % 3, n = i / 1536;
        const int kk = s * 32 + (l >> 4) * 8 + j;
        const int n2 = n * 16 + (l & 15);
        const float w = (kk < NH1 && n2 < NH2) ? W2[kk * NH2 + n2] : 0.f;
        wF2[i] = (_Float16)w;
    }
}

__global__ void prep_qh(const float* __restrict__ q, const float* __restrict__ W1,
                        const float* __restrict__ b1, float* __restrict__ wQh)
{
    const int idx = blockIdx.x * blockDim.x + threadIdx.x;
    if (idx >= NB * NH1) return;
    const int b = idx / NH1;
    const int h = idx - b * NH1;
    const float* qb = q + (size_t)b * DD;
    float acc = b1[h];
#pragma unroll 8
    for (int d = 0; d < DD; ++d)
        acc += qb[d] * (W1[d * NH1 + h] + W1[(128 + d) * NH1 + h]);
    wQh[idx] = acc;
}

__global__ __launch_bounds__(256, 2)
void attn_main(const float* __restrict__ q, const float* __restrict__ k,
               const float* __restrict__ v, const int* __restrict__ mask,
               const float* __restrict__ Wf, const float* __restrict__ b2g,
               const float* __restrict__ bf,
               const float* __restrict__ wQh, const _Float16* __restrict__ wF1,
               const _Float16* __restrict__ wF2, float* __restrict__ out)
{
    __shared__ __align__(16) _Float16 sWF1[5 * 4 * 64 * 8];   // 20480 B
    __shared__ __align__(16) char sPool[4 * 16 * 192];        // per-wave h1 (12288 B); reused as sVred
    __shared__ float sQh[80];
    __shared__ float sWf[48];
    __shared__ float sB2[48];
    __shared__ float sLogit[208];
    __shared__ float sAttn[208];
    __shared__ float sRed[8];

    const int b    = blockIdx.x;
    const int tid  = threadIdx.x;
    const int wid  = tid >> 6;
    const int lane = tid & 63;
    const int lr   = lane & 15;
    const int lg   = lane >> 4;
    const float bfv = bf[0];

    // hoisted mask load (coalesced, overlaps everything below)
    int mymask = 0;
    if (tid < TT) mymask = mask[(size_t)b * TT + tid];

    if (tid < 80)                  sQh[tid] = wQh[(size_t)b * NH1 + tid];
    else if (tid < 128) { const int c = tid - 80;  sWf[c] = (c < NH2) ? Wf[c]  : 0.f; }
    else if (tid < 176) { const int c = tid - 128; sB2[c] = (c < NH2) ? b2g[c] : 0.f; }

    // stage layer-1 weight fragments into LDS (lane-contiguous, conflict-free reads)
    {
        f32x4* dst = (f32x4*)sWF1;
        const f32x4* src = (const f32x4*)wF1;
        for (int i = tid; i < 1280; i += 256) dst[i] = src[i];
    }

    // q held as packed fp16 (8 VGPRs): qh0 = q[lg*8..+7], qh1 = q[32+lg*8..+7]
    half8 qh0, qh1;
    {
        const float* qb = q + (size_t)b * DD;
#pragma unroll
        for (int j = 0; j < 8; ++j) qh0[j] = (_Float16)qb[lg * 8 + j];
#pragma unroll
        for (int j = 0; j < 8; ++j) qh1[j] = (_Float16)qb[32 + lg * 8 + j];
    }

    // zero-pad my wave's h1 cols 80..95 (slots 10,11), swizzled
    char* myH1 = sPool + wid * 3072;
    if (lane < 32) {
        const int row = lane >> 1;
        const int slotL = 10 + (lane & 1);
        const f32x4 z4 = {};
        *(f32x4*)(myH1 + row * 192 + ((slotL ^ (row & 3)) << 4)) = z4;
    }

    __syncthreads();   // sWF1 / sQh / sWf / sB2 ready

    const half8* sF1v = (const half8*)sWF1;
    const half8* gF2  = (const half8*)wF2;

    // ---- fused per-tile: layer1 -> per-wave LDS -> layer2 -> logits ----
    for (int mt = wid; mt < 13; mt += 4) {
        const int t = min(mt * 16 + lr, TT - 1);   // clamped; rows >=200 give discarded logits
        const float* krow = k + ((size_t)b * TT + t) * DD;
        const f32x4 kv0 = *(const f32x4*)(krow + lg * 8);
        const f32x4 kv1 = *(const f32x4*)(krow + lg * 8 + 4);
        const f32x4 kv2 = *(const f32x4*)(krow + 32 + lg * 8);
        const f32x4 kv3 = *(const f32x4*)(krow + 32 + lg * 8 + 4);

        half8 af[4];
#pragma unroll
        for (int j = 0; j < 4; ++j) {
            af[0][j] = (_Float16)kv0[j];  af[0][j + 4] = (_Float16)kv1[j];
            af[1][j] = (_Float16)kv2[j];  af[1][j + 4] = (_Float16)kv3[j];
        }
        af[2] = qh0 * af[0];   // packed fp16 multiplies (q*k)
        af[3] = qh1 * af[1];

        // layer 1: one accumulator at a time, epilogue inlined (small live set)
#pragma unroll
        for (int n = 0; n < 5; ++n) {
            f32x4 acc = {};
#pragma unroll
            for (int s = 0; s < 4; ++s)
                acc = __builtin_amdgcn_mfma_f32_16x16x32_f16(af[s], sF1v[(n * 4 + s) * 64 + lane], acc, 0, 0, 0);

            const int hcol = n * 16 + lr;
            const float qh = sQh[hcol];
            const int slot   = hcol >> 3;
            const int within = (hcol & 7) * 2;
#pragma unroll
            for (int j = 0; j < 4; ++j) {
                const int r = lg * 4 + j;
                const float hv = fmaxf(acc[j] + qh, 0.f);
                *(_Float16*)(myH1 + r * 192 + ((slot ^ (r & 3)) << 4) + within) = (_Float16)hv;
            }
        }

        // layer 2 on this tile (reads only rows this wave just wrote)
        half8 a2[3];
#pragma unroll
        for (int s = 0; s < 3; ++s)
            a2[s] = *(const half8*)(myH1 + lr * 192 + (((s * 4 + lg) ^ (lr & 3)) << 4));

        float p0 = 0.f, p1 = 0.f, p2 = 0.f, p3 = 0.f;
#pragma unroll
        for (int n = 0; n < 3; ++n) {
            f32x4 acc2 = {};
#pragma unroll
            for (int s = 0; s < 3; ++s)
                acc2 = __builtin_amdgcn_mfma_f32_16x16x32_f16(a2[s], gF2[(n * 3 + s) * 64 + lane], acc2, 0, 0, 0);

            const int hcol = n * 16 + lr;
            const float wf = sWf[hcol];
            const float bb = sB2[hcol];
            p0 += fmaxf(acc2[0] + bb, 0.f) * wf;
            p1 += fmaxf(acc2[1] + bb, 0.f) * wf;
            p2 += fmaxf(acc2[2] + bb, 0.f) * wf;
            p3 += fmaxf(acc2[3] + bb, 0.f) * wf;
        }
#pragma unroll
        for (int off = 1; off < 16; off <<= 1) {
            p0 += __shfl_xor(p0, off);
            p1 += __shfl_xor(p1, off);
            p2 += __shfl_xor(p2, off);
            p3 += __shfl_xor(p3, off);
        }
        if (lr == 0) {
            const int rbase = mt * 16 + lg * 4;
            sLogit[rbase + 0] = p0 + bfv;
            sLogit[rbase + 1] = p1 + bfv;
            sLogit[rbase + 2] = p2 + bfv;
            sLogit[rbase + 3] = p3 + bfv;
        }
    }
    __syncthreads();

    // ---------------- masked softmax over T ----------------
    {
        const int t = tid;
        float lgv = -3.0e38f;
        if (t < TT) lgv = mymask ? sLogit[t] : -4294967295.0f;
        float m = lgv;
#pragma unroll
        for (int off = 32; off > 0; off >>= 1) m = fmaxf(m, __shfl_xor(m, off));
        if (lane == 0) sRed[wid] = m;
        __syncthreads();
        const float M = fmaxf(fmaxf(sRed[0], sRed[1]), fmaxf(sRed[2], sRed[3]));
        float e = (t < TT) ? __expf(lgv - M) : 0.f;
        float s = e;
#pragma unroll
        for (int off = 32; off > 0; off >>= 1) s += __shfl_xor(s, off);
        if (lane == 0) sRed[4 + wid] = s;
        __syncthreads();
        const float S = sRed[4] + sRed[5] + sRed[6] + sRed[7];
        if (t < TT) sAttn[t] = e / S;
    }
    __syncthreads();

    // ---------------- weighted sum over v ----------------
    float* sVred = (float*)sPool;   // h1 pool is dead now
    {
        const int dq = (tid & 15) * 4;
        const int g  = tid >> 4;
        const float* vb = v + (size_t)b * (TT * DD);
        f32x4 acc = {};
#pragma unroll
        for (int i = 0; i < 13; ++i) {
            const int t0 = g + i * 16;
            if (t0 < TT) {
                const f32x4 vv = *(const f32x4*)(vb + t0 * DD + dq);
                acc += vv * sAttn[t0];
            }
        }
        *(f32x4*)(&sVred[g * 64 + dq]) = acc;
    }
    __syncthreads();
    if (tid < 64) {
        float r = 0.f;
#pragma unroll
        for (int gg = 0; gg < 16; ++gg) r += sVred[gg * 64 + tid];
        out[(size_t)b * DD + tid] = r;
    }
}

extern "C" void kernel_launch(void* const* d_in, const int* in_sizes, int n_in,
                              void* d_out, int out_size, void* d_ws, size_t ws_size,
                              hipStream_t stream)
{
    const float* q   = (const float*)d_in[0];
    const float* k   = (const float*)d_in[1];
    const float* v   = (const float*)d_in[2];
    const int*  mask = (const int*)  d_in[3];
    const float* W1  = (const float*)d_in[4];
    const float* b1  = (const float*)d_in[5];
    const float* W2  = (const float*)d_in[6];
    const float* b2  = (const float*)d_in[7];
    const float* Wf  = (const float*)d_in[8];
    const float* bf  = (const float*)d_in[9];
    float* out = (float*)d_out;

    char* ws = (char*)d_ws;
    float*    wQh = (float*)   (ws + OFF_QH);
    _Float16* wF1 = (_Float16*)(ws + OFF_F1);
    _Float16* wF2 = (_Float16*)(ws + OFF_F2);

    prep_weights<<<16, 256, 0, stream>>>(W1, W2, wF1, wF2);
    prep_qh<<<(NB * NH1 + 255) / 256, 256, 0, stream>>>(q, W1, b1, wQh);
    attn_main<<<NB, 256, 0, stream>>>(q, k, v, mask, Wf, b2, bf, wQh, wF1, wF2, out);
}

// Round 5
// 102.658 us; speedup vs baseline: 3.1627x; 1.3365x over previous
//
#include <hip/hip_runtime.h>
#include <cstddef>
#include <cmath>

#define NB  4096
#define TT  200
#define DD  64
#define NH1 80
#define NH2 40

typedef _Float16 half8 __attribute__((ext_vector_type(8)));
typedef float    f32x4 __attribute__((ext_vector_type(4)));

// ---- workspace layout (bytes) ----
// wQh [4096][80] f32 : q@(W1a+W1c) + b1
// wF1 : layer-1 B fragments, lane-major: [(n*4+s)*64 + lane] -> half8  (20480 B)
// wF2 : layer-2 B fragments, lane-major: [(n*3+s)*64 + lane] -> half8  (9216 B)
static const size_t OFF_QH = 0;
static const size_t OFF_F1 = (size_t)NB * NH1 * 4;
static const size_t OFF_F2 = OFF_F1 + (size_t)5 * 4 * 64 * 8 * 2;

__global__ void prep_weights(const float* __restrict__ W1, const float* __restrict__ W2,
                             _Float16* __restrict__ wF1, _Float16* __restrict__ wF2)
{
    const int tid = blockIdx.x * blockDim.x + threadIdx.x;
    const int stride = blockDim.x * gridDim.x;
    // layer-1 fragments: value = B[kk][h], h = n*16+(l&15), kk = s*32+(l>>4)*8+j
    for (int i = tid; i < 5 * 4 * 64 * 8; i += stride) {
        const int j = i & 7, l = (i >> 3) & 63, s = (i >> 9) & 3, n = i >> 11;
        const int h  = n * 16 + (l & 15);
        const int kk = s * 32 + (l >> 4) * 8 + j;
        const float w = (kk < 64) ? (W1[(64 + kk) * NH1 + h] - W1[(128 + kk) * NH1 + h])
                                  :  W1[(128 + kk) * NH1 + h];
        wF1[i] = (_Float16)w;
    }
    // layer-2 fragments: value = W2[kk][n2], n2 = n*16+(l&15), kk = s*32+(l>>4)*8+j
    for (int i = tid; i < 3 * 3 * 64 * 8; i += stride) {
        const int j = i & 7, l = (i >> 3) & 63;
        const int s = (i >> 9) % 3, n = i / 1536;
        const int kk = s * 32 + (l >> 4) * 8 + j;
        const int n2 = n * 16 + (l & 15);
        const float w = (kk < NH1 && n2 < NH2) ? W2[kk * NH2 + n2] : 0.f;
        wF2[i] = (_Float16)w;
    }
}

__global__ void prep_qh(const float* __restrict__ q, const float* __restrict__ W1,
                        const float* __restrict__ b1, float* __restrict__ wQh)
{
    const int idx = blockIdx.x * blockDim.x + threadIdx.x;
    if (idx >= NB * NH1) return;
    const int b = idx / NH1;
    const int h = idx - b * NH1;
    const float* qb = q + (size_t)b * DD;
    float acc = b1[h];
#pragma unroll 8
    for (int d = 0; d < DD; ++d)
        acc += qb[d] * (W1[d * NH1 + h] + W1[(128 + d) * NH1 + h]);
    wQh[idx] = acc;
}

// one wave per b; online (flash-style) masked softmax + v accumulation fused in the tile loop
__global__ __launch_bounds__(256, 2)
void attn_main(const float* __restrict__ q, const float* __restrict__ k,
               const float* __restrict__ v, const int* __restrict__ mask,
               const float* __restrict__ Wf, const float* __restrict__ b2g,
               const float* __restrict__ bf,
               const float* __restrict__ wQh, const _Float16* __restrict__ wF1,
               const _Float16* __restrict__ wF2, float* __restrict__ out)
{
    __shared__ __align__(16) _Float16 sWF1[5 * 4 * 64 * 8];   // 20480 B
    __shared__ __align__(16) char sH1[4 * 3072];              // per-wave h1, swizzled (12288 B)
    __shared__ float sBias[4][208];                           // per-wave mask bias (3328 B)

    const int tid  = threadIdx.x;
    const int wid  = tid >> 6;
    const int lane = tid & 63;
    const int lr   = lane & 15;
    const int lg   = lane >> 4;
    const int b    = blockIdx.x * 4 + wid;      // each wave owns one batch row
    const float bfv = bf[0];

    // stage layer-1 weight fragments into LDS (block-shared)
    {
        f32x4* dst = (f32x4*)sWF1;
        const f32x4* src = (const f32x4*)wF1;
        for (int i = tid; i < 1280; i += 256) dst[i] = src[i];
    }

    // per-wave mask bias: +big = keep, CONST_MIN = masked, -inf = pad rows (t>=200)
    for (int i = lane; i < 208; i += 64) {
        float bv;
        if (i < TT) bv = mask[(size_t)b * TT + i] ? 3.0e38f : -4294967295.0f;
        else        bv = -INFINITY;
        sBias[wid][i] = bv;
    }

    // layer-2 B fragments in registers (loop-invariant, 36 VGPR)
    half8 w2f[9];
#pragma unroll
    for (int i = 0; i < 9; ++i) w2f[i] = ((const half8*)wF2)[i * 64 + lane];

    // per-lane slices of qh / Wf / b2 (only hcol = n*16+lr is ever needed by this lane)
    float qhr[5];
#pragma unroll
    for (int n = 0; n < 5; ++n) qhr[n] = wQh[(size_t)b * NH1 + n * 16 + lr];
    float wfr[3], bbr[3];
#pragma unroll
    for (int n = 0; n < 3; ++n) {
        const int hc = n * 16 + lr;
        wfr[n] = (hc < NH2) ? Wf[hc]  : 0.f;
        bbr[n] = (hc < NH2) ? b2g[hc] : 0.f;
    }

    // q in packed fp16
    half8 qh0, qh1;
    {
        const float* qb = q + (size_t)b * DD;
#pragma unroll
        for (int j = 0; j < 8; ++j) qh0[j] = (_Float16)qb[lg * 8 + j];
#pragma unroll
        for (int j = 0; j < 8; ++j) qh1[j] = (_Float16)qb[32 + lg * 8 + j];
    }

    // zero-pad my wave's h1 cols 80..95 (slots 10,11), swizzled
    char* myH1 = sH1 + wid * 3072;
    if (lane < 32) {
        const int row = lane >> 1;
        const int slotL = 10 + (lane & 1);
        const f32x4 z4 = {};
        *(f32x4*)(myH1 + row * 192 + ((slotL ^ (row & 3)) << 4)) = z4;
    }

    __syncthreads();   // sWF1 ready (sBias/h1-pad are wave-private)

    const half8* sF1v = (const half8*)sWF1;
    const float* vb   = v + (size_t)b * (TT * DD);

    float m = -INFINITY, s = 0.f, acc = 0.f;   // online softmax state; acc for d = lane

    for (int mt = 0; mt < 13; ++mt) {
        // ---- layer 1 inputs ----
        const int t = min(mt * 16 + lr, TT - 1);   // clamped; pad rows killed by bias
        const float* krow = k + ((size_t)b * TT + t) * DD;
        const f32x4 kv0 = *(const f32x4*)(krow + lg * 8);
        const f32x4 kv1 = *(const f32x4*)(krow + lg * 8 + 4);
        const f32x4 kv2 = *(const f32x4*)(krow + 32 + lg * 8);
        const f32x4 kv3 = *(const f32x4*)(krow + 32 + lg * 8 + 4);

        half8 af[4];
#pragma unroll
        for (int j = 0; j < 4; ++j) {
            af[0][j] = (_Float16)kv0[j];  af[0][j + 4] = (_Float16)kv1[j];
            af[1][j] = (_Float16)kv2[j];  af[1][j + 4] = (_Float16)kv3[j];
        }
        af[2] = qh0 * af[0];
        af[3] = qh1 * af[1];

        // ---- layer 1 MFMA + inline relu epilogue to per-wave LDS ----
#pragma unroll
        for (int n = 0; n < 5; ++n) {
            f32x4 a = {};
#pragma unroll
            for (int ss = 0; ss < 4; ++ss)
                a = __builtin_amdgcn_mfma_f32_16x16x32_f16(af[ss], sF1v[(n * 4 + ss) * 64 + lane], a, 0, 0, 0);
            const int slot   = (n * 16 + lr) >> 3;
            const int within = ((n * 16 + lr) & 7) * 2;
#pragma unroll
            for (int j = 0; j < 4; ++j) {
                const int r = lg * 4 + j;
                const float hv = fmaxf(a[j] + qhr[n], 0.f);
                *(_Float16*)(myH1 + r * 192 + ((slot ^ (r & 3)) << 4) + within) = (_Float16)hv;
            }
        }

        // ---- layer 2 (wave-private rows) ----
        half8 a2[3];
#pragma unroll
        for (int ss = 0; ss < 3; ++ss)
            a2[ss] = *(const half8*)(myH1 + lr * 192 + (((ss * 4 + lg) ^ (lr & 3)) << 4));

        float p0 = 0.f, p1 = 0.f, p2 = 0.f, p3 = 0.f;
#pragma unroll
        for (int n = 0; n < 3; ++n) {
            f32x4 c2 = {};
#pragma unroll
            for (int ss = 0; ss < 3; ++ss)
                c2 = __builtin_amdgcn_mfma_f32_16x16x32_f16(a2[ss], w2f[n * 3 + ss], c2, 0, 0, 0);
            p0 += fmaxf(c2[0] + bbr[n], 0.f) * wfr[n];
            p1 += fmaxf(c2[1] + bbr[n], 0.f) * wfr[n];
            p2 += fmaxf(c2[2] + bbr[n], 0.f) * wfr[n];
            p3 += fmaxf(c2[3] + bbr[n], 0.f) * wfr[n];
        }
        // butterfly over the 16-lane column groups: all lanes get the row sums
#pragma unroll
        for (int off = 1; off < 16; off <<= 1) {
            p0 += __shfl_xor(p0, off);
            p1 += __shfl_xor(p1, off);
            p2 += __shfl_xor(p2, off);
            p3 += __shfl_xor(p3, off);
        }

        // broadcast the 16 tile logits to every lane: row g*4+j held by lane g*16 in p_j
        float l[16];
#pragma unroll
        for (int g = 0; g < 4; ++g) {
            const int src = g << 4;
            l[g * 4 + 0] = __shfl(p0, src);
            l[g * 4 + 1] = __shfl(p1, src);
            l[g * 4 + 2] = __shfl(p2, src);
            l[g * 4 + 3] = __shfl(p3, src);
        }

        // ---- online masked softmax + v accumulation (all lanes redundantly compute w) ----
        float lmax = -INFINITY;
#pragma unroll
        for (int j = 0; j < 16; ++j) {
            l[j] = fminf(l[j] + bfv, sBias[wid][mt * 16 + j]);
            lmax = fmaxf(lmax, l[j]);
        }
        const float mnew  = fmaxf(m, lmax);
        const float scale = __expf(m - mnew);
        acc *= scale;
        s   *= scale;
        m    = mnew;
#pragma unroll
        for (int j = 0; j < 16; ++j) {
            const float w = __expf(l[j] - mnew);
            s += w;
            const int tj = min(mt * 16 + j, TT - 1);
            acc = fmaf(w, vb[tj * DD + lane], acc);
        }
    }

    out[(size_t)b * DD + lane] = acc / s;
}

extern "C" void kernel_launch(void* const* d_in, const int* in_sizes, int n_in,
                              void* d_out, int out_size, void* d_ws, size_t ws_size,
                              hipStream_t stream)
{
    const float* q   = (const float*)d_in[0];
    const float* k   = (const float*)d_in[1];
    const float* v   = (const float*)d_in[2];
    const int*  mask = (const int*)  d_in[3];
    const float* W1  = (const float*)d_in[4];
    const float* b1  = (const float*)d_in[5];
    const float* W2  = (const float*)d_in[6];
    const float* b2  = (const float*)d_in[7];
    const float* Wf  = (const float*)d_in[8];
    const float* bf  = (const float*)d_in[9];
    float* out = (float*)d_out;

    char* ws = (char*)d_ws;
    float*    wQh = (float*)   (ws + OFF_QH);
    _Float16* wF1 = (_Float16*)(ws + OFF_F1);
    _Float16* wF2 = (_Float16*)(ws + OFF_F2);

    prep_weights<<<16, 256, 0, stream>>>(W1, W2, wF1, wF2);
    prep_qh<<<(NB * NH1 + 255) / 256, 256, 0, stream>>>(q, W1, b1, wQh);
    attn_main<<<NB / 4, 256, 0, stream>>>(q, k, v, mask, Wf, b2, bf, wQh, wF1, wF2, out);
}

// Round 6
// 101.337 us; speedup vs baseline: 3.2040x; 1.0130x over previous
//
#include <hip/hip_runtime.h>
#include <cstddef>
#include <cmath>

#define NB  4096
#define TT  200
#define DD  64
#define NH1 80
#define NH2 40

typedef _Float16 half8 __attribute__((ext_vector_type(8)));
typedef float    f32x4 __attribute__((ext_vector_type(4)));

// ---- workspace layout (bytes) ----
// wQh [4096][80] f32 : q@(W1a+W1c) + b1
// wF1 : layer-1 B fragments, lane-major: [(n*4+s)*64 + lane] -> half8  (20480 B)
// wF2 : layer-2 B fragments, lane-major: [(n*3+s)*64 + lane] -> half8  (9216 B)
static const size_t OFF_QH = 0;
static const size_t OFF_F1 = (size_t)NB * NH1 * 4;
static const size_t OFF_F2 = OFF_F1 + (size_t)5 * 4 * 64 * 8 * 2;

__global__ void prep_weights(const float* __restrict__ W1, const float* __restrict__ W2,
                             _Float16* __restrict__ wF1, _Float16* __restrict__ wF2)
{
    const int tid = blockIdx.x * blockDim.x + threadIdx.x;
    const int stride = blockDim.x * gridDim.x;
    // layer-1 fragments: value = B[kk][h], h = n*16+(l&15), kk = s*32+(l>>4)*8+j
    for (int i = tid; i < 5 * 4 * 64 * 8; i += stride) {
        const int j = i & 7, l = (i >> 3) & 63, s = (i >> 9) & 3, n = i >> 11;
        const int h  = n * 16 + (l & 15);
        const int kk = s * 32 + (l >> 4) * 8 + j;
        const float w = (kk < 64) ? (W1[(64 + kk) * NH1 + h] - W1[(128 + kk) * NH1 + h])
                                  :  W1[(128 + kk) * NH1 + h];
        wF1[i] = (_Float16)w;
    }
    // layer-2 fragments: value = W2[kk][n2], n2 = n*16+(l&15), kk = s*32+(l>>4)*8+j
    for (int i = tid; i < 3 * 3 * 64 * 8; i += stride) {
        const int j = i & 7, l = (i >> 3) & 63;
        const int s = (i >> 9) % 3, n = i / 1536;
        const int kk = s * 32 + (l >> 4) * 8 + j;
        const int n2 = n * 16 + (l & 15);
        const float w = (kk < NH1 && n2 < NH2) ? W2[kk * NH2 + n2] : 0.f;
        wF2[i] = (_Float16)w;
    }
}

__global__ void prep_qh(const float* __restrict__ q, const float* __restrict__ W1,
                        const float* __restrict__ b1, float* __restrict__ wQh)
{
    const int idx = blockIdx.x * blockDim.x + threadIdx.x;
    if (idx >= NB * NH1) return;
    const int b = idx / NH1;
    const int h = idx - b * NH1;
    const float* qb = q + (size_t)b * DD;
    float acc = b1[h];
#pragma unroll 8
    for (int d = 0; d < DD; ++d)
        acc += qb[d] * (W1[d * NH1 + h] + W1[(128 + d) * NH1 + h]);
    wQh[idx] = acc;
}

// one wave per b; group-split online softmax; k register double-buffer
__global__ __launch_bounds__(256, 2)
void attn_main(const float* __restrict__ q, const float* __restrict__ k,
               const float* __restrict__ v, const int* __restrict__ mask,
               const float* __restrict__ Wf, const float* __restrict__ b2g,
               const float* __restrict__ bf,
               const float* __restrict__ wQh, const _Float16* __restrict__ wF1,
               const _Float16* __restrict__ wF2, float* __restrict__ out)
{
    __shared__ __align__(16) _Float16 sWF1[5 * 4 * 64 * 8];   // 20480 B
    __shared__ __align__(16) char sH1[4 * 3072];              // per-wave h1, swizzled
    __shared__ __align__(16) float sBias[4][208];             // per-wave mask bias

    const int tid  = threadIdx.x;
    const int wid  = tid >> 6;
    const int lane = tid & 63;
    const int lr   = lane & 15;
    const int lg   = lane >> 4;
    const int b    = blockIdx.x * 4 + wid;      // each wave owns one batch row
    const int d0   = lr * 4;                    // this lane's v/out column slice
    const float bfv = bf[0];

    // stage layer-1 weight fragments into LDS (block-shared)
    {
        f32x4* dst = (f32x4*)sWF1;
        const f32x4* src = (const f32x4*)wF1;
        for (int i = tid; i < 1280; i += 256) dst[i] = src[i];
    }

    // per-wave mask bias: +big = keep, CONST_MIN = masked, -inf = pad rows (t>=200)
    for (int i = lane; i < 208; i += 64) {
        float bv;
        if (i < TT) bv = mask[(size_t)b * TT + i] ? 3.0e38f : -4294967295.0f;
        else        bv = -INFINITY;
        sBias[wid][i] = bv;
    }

    // layer-2 B fragments in registers (loop-invariant)
    half8 w2f[9];
#pragma unroll
    for (int i = 0; i < 9; ++i) w2f[i] = ((const half8*)wF2)[i * 64 + lane];

    // per-lane slices of qh / Wf / b2
    float qhr[5];
#pragma unroll
    for (int n = 0; n < 5; ++n) qhr[n] = wQh[(size_t)b * NH1 + n * 16 + lr];
    float wfr[3], bbr[3];
#pragma unroll
    for (int n = 0; n < 3; ++n) {
        const int hc = n * 16 + lr;
        wfr[n] = (hc < NH2) ? Wf[hc]  : 0.f;
        bbr[n] = (hc < NH2) ? b2g[hc] : 0.f;
    }

    // q in packed fp16
    half8 qh0, qh1;
    {
        const float* qb = q + (size_t)b * DD;
#pragma unroll
        for (int j = 0; j < 8; ++j) qh0[j] = (_Float16)qb[lg * 8 + j];
#pragma unroll
        for (int j = 0; j < 8; ++j) qh1[j] = (_Float16)qb[32 + lg * 8 + j];
    }

    // zero-pad my wave's h1 cols 80..95 (slots 10,11), swizzled
    char* myH1 = sH1 + wid * 3072;
    if (lane < 32) {
        const int row = lane >> 1;
        const int slotL = 10 + (lane & 1);
        const f32x4 z4 = {};
        *(f32x4*)(myH1 + row * 192 + ((slotL ^ (row & 3)) << 4)) = z4;
    }

    __syncthreads();   // sWF1 ready

    const half8* sF1v = (const half8*)sWF1;
    const float* vb   = v + (size_t)b * (TT * DD);

    // per-GROUP online softmax state (rows mt*16+lg*4+{0..3}; d-cols d0..d0+3)
    float m = -INFINITY, s = 0.f;
    f32x4 acc = {};

    // prologue: k tile 0 into registers
    f32x4 kc0, kc1, kc2, kc3;
    {
        const float* krow = k + ((size_t)b * TT + lr) * DD;
        kc0 = *(const f32x4*)(krow + lg * 8);
        kc1 = *(const f32x4*)(krow + lg * 8 + 4);
        kc2 = *(const f32x4*)(krow + 32 + lg * 8);
        kc3 = *(const f32x4*)(krow + 32 + lg * 8 + 4);
    }

    for (int mt = 0; mt < 13; ++mt) {
        // ---- v loads for this tile (issued early; consumed at bottom) ----
        const int tr = mt * 16 + lg * 4;
        const f32x4 vA = *(const f32x4*)(vb + (size_t)min(tr + 0, TT - 1) * DD + d0);
        const f32x4 vB = *(const f32x4*)(vb + (size_t)min(tr + 1, TT - 1) * DD + d0);
        const f32x4 vC = *(const f32x4*)(vb + (size_t)min(tr + 2, TT - 1) * DD + d0);
        const f32x4 vD = *(const f32x4*)(vb + (size_t)min(tr + 3, TT - 1) * DD + d0);

        // ---- convert current k to fp16 A-fragments ----
        half8 af0, af1;
#pragma unroll
        for (int j = 0; j < 4; ++j) {
            af0[j] = (_Float16)kc0[j];  af0[j + 4] = (_Float16)kc1[j];
            af1[j] = (_Float16)kc2[j];  af1[j + 4] = (_Float16)kc3[j];
        }
        const half8 af2 = qh0 * af0;
        const half8 af3 = qh1 * af1;

        // ---- prefetch next k tile (register double-buffer) ----
        if (mt < 12) {
            const int t = min((mt + 1) * 16 + lr, TT - 1);
            const float* krow = k + ((size_t)b * TT + t) * DD;
            kc0 = *(const f32x4*)(krow + lg * 8);
            kc1 = *(const f32x4*)(krow + lg * 8 + 4);
            kc2 = *(const f32x4*)(krow + 32 + lg * 8);
            kc3 = *(const f32x4*)(krow + 32 + lg * 8 + 4);
        }

        // ---- layer 1 MFMA, qh folded into C-init, relu -> per-wave LDS ----
#pragma unroll
        for (int n = 0; n < 5; ++n) {
            f32x4 a = { qhr[n], qhr[n], qhr[n], qhr[n] };
            a = __builtin_amdgcn_mfma_f32_16x16x32_f16(af0, sF1v[(n * 4 + 0) * 64 + lane], a, 0, 0, 0);
            a = __builtin_amdgcn_mfma_f32_16x16x32_f16(af1, sF1v[(n * 4 + 1) * 64 + lane], a, 0, 0, 0);
            a = __builtin_amdgcn_mfma_f32_16x16x32_f16(af2, sF1v[(n * 4 + 2) * 64 + lane], a, 0, 0, 0);
            a = __builtin_amdgcn_mfma_f32_16x16x32_f16(af3, sF1v[(n * 4 + 3) * 64 + lane], a, 0, 0, 0);
            const int slot   = (n * 16 + lr) >> 3;
            const int within = ((n * 16 + lr) & 7) * 2;
#pragma unroll
            for (int j = 0; j < 4; ++j) {
                const int r = lg * 4 + j;
                const float hv = fmaxf(a[j], 0.f);
                *(_Float16*)(myH1 + r * 192 + ((slot ^ (r & 3)) << 4) + within) = (_Float16)hv;
            }
        }

        // ---- layer 2 (wave-private rows), b2 folded into C-init ----
        half8 a2_0 = *(const half8*)(myH1 + lr * 192 + (((0 * 4 + lg) ^ (lr & 3)) << 4));
        half8 a2_1 = *(const half8*)(myH1 + lr * 192 + (((1 * 4 + lg) ^ (lr & 3)) << 4));
        half8 a2_2 = *(const half8*)(myH1 + lr * 192 + (((2 * 4 + lg) ^ (lr & 3)) << 4));

        float p0 = 0.f, p1 = 0.f, p2 = 0.f, p3 = 0.f;
#pragma unroll
        for (int n = 0; n < 3; ++n) {
            f32x4 c2 = { bbr[n], bbr[n], bbr[n], bbr[n] };
            c2 = __builtin_amdgcn_mfma_f32_16x16x32_f16(a2_0, w2f[n * 3 + 0], c2, 0, 0, 0);
            c2 = __builtin_amdgcn_mfma_f32_16x16x32_f16(a2_1, w2f[n * 3 + 1], c2, 0, 0, 0);
            c2 = __builtin_amdgcn_mfma_f32_16x16x32_f16(a2_2, w2f[n * 3 + 2], c2, 0, 0, 0);
            p0 = fmaf(fmaxf(c2[0], 0.f), wfr[n], p0);
            p1 = fmaf(fmaxf(c2[1], 0.f), wfr[n], p1);
            p2 = fmaf(fmaxf(c2[2], 0.f), wfr[n], p2);
            p3 = fmaf(fmaxf(c2[3], 0.f), wfr[n], p3);
        }
        // butterfly over the 16-lane column group: rows lg*4+{0..3} summed
#pragma unroll
        for (int off = 1; off < 16; off <<= 1) {
            p0 += __shfl_xor(p0, off);
            p1 += __shfl_xor(p1, off);
            p2 += __shfl_xor(p2, off);
            p3 += __shfl_xor(p3, off);
        }

        // ---- group-private online masked softmax + v accumulation ----
        const f32x4 bias4 = *(const f32x4*)&sBias[wid][mt * 16 + lg * 4];
        const float l0 = fminf(p0, bias4[0]) + bfv;
        const float l1 = fminf(p1, bias4[1]) + bfv;
        const float l2 = fminf(p2, bias4[2]) + bfv;
        const float l3 = fminf(p3, bias4[3]) + bfv;
        const float lmax = fmaxf(fmaxf(l0, l1), fmaxf(l2, l3));
        const float mnew = fmaxf(m, lmax);
        const float sc = __expf(m - mnew);
        const float w0 = __expf(l0 - mnew);
        const float w1 = __expf(l1 - mnew);
        const float w2 = __expf(l2 - mnew);
        const float w3 = __expf(l3 - mnew);
        s = s * sc + (w0 + w1 + w2 + w3);
        acc *= sc;
        acc += vA * w0;
        acc += vB * w1;
        acc += vC * w2;
        acc += vD * w3;
        m = mnew;
    }

    // ---- merge the 4 group states (lanes differ in bits 4,5) ----
    float mo = fmaxf(m, __shfl_xor(m, 16));
    mo = fmaxf(mo, __shfl_xor(mo, 32));
    const float f = __expf(m - mo);
    s *= f;
    acc *= f;
    s += __shfl_xor(s, 16);
    s += __shfl_xor(s, 32);
#pragma unroll
    for (int e = 0; e < 4; ++e) {
        float t = acc[e];
        t += __shfl_xor(t, 16);
        t += __shfl_xor(t, 32);
        acc[e] = t;
    }
    if (lg == 0) {
        const f32x4 res = acc / s;
        *(f32x4*)(out + (size_t)b * DD + d0) = res;
    }
}

extern "C" void kernel_launch(void* const* d_in, const int* in_sizes, int n_in,
                              void* d_out, int out_size, void* d_ws, size_t ws_size,
                              hipStream_t stream)
{
    const float* q   = (const float*)d_in[0];
    const float* k   = (const float*)d_in[1];
    const float* v   = (const float*)d_in[2];
    const int*  mask = (const int*)  d_in[3];
    const float* W1  = (const float*)d_in[4];
    const float* b1  = (const float*)d_in[5];
    const float* W2  = (const float*)d_in[6];
    const float* b2  = (const float*)d_in[7];
    const float* Wf  = (const float*)d_in[8];
    const float* bf  = (const float*)d_in[9];
    float* out = (float*)d_out;

    char* ws = (char*)d_ws;
    float*    wQh = (float*)   (ws + OFF_QH);
    _Float16* wF1 = (_Float16*)(ws + OFF_F1);
    _Float16* wF2 = (_Float16*)(ws + OFF_F2);

    prep_weights<<<16, 256, 0, stream>>>(W1, W2, wF1, wF2);
    prep_qh<<<(NB * NH1 + 255) / 256, 256, 0, stream>>>(q, W1, b1, wQh);
    attn_main<<<NB / 4, 256, 0, stream>>>(q, k, v, mask, Wf, b2, bf, wQh, wF1, wF2, out);
}